// Round 6
// baseline (259.924 us; speedup 1.0000x reference)
//
#include <hip/hip_runtime.h>
#include <hip/hip_bf16.h>

// ODE-RNN: B=256, T=64, H=256, D=512.
// v23 = v22 + asm register-pinning of ALL three streamed/pinned weight matrices.
//   UNIFIED POST-MORTEM (v17/v21/v22 all ~6800-7300 cy/step, VGPR_Count=128):
//   "pinned" weights never fit (32 uint4 = 128 VGPR alone). The allocator
//   REMATERIALIZES loop-invariant loads instead of spilling -> every step
//   re-streams W~ (x2 stages) + z + r from L2: ~512 KB/block/step / 56 B/cy/CU
//   ~ 9100 cy/step == measured. The budget at waves_per_eu(2,2) is 256 VGPR
//   (waves/CU halves at 64/128/256), but the cost model prefers 128 + remat.
//   Fix: semantic pin — asm volatile("" : "+v"(x)) on each weight component
//   makes the value opaque: not rematerializable, must stay resident.
//   48 uint4 = 192 VGPR pinned (W~ + Wz + Wr); live ~240 <= 256. Wn in LDS.
//   Main loop now has ZERO VMEM. nlds staged BEFORE pin loads (transient
//   staging pressure off the peak).
//   Canaries: VGPR_Count must read ~240-256 (128 = pin failed);
//   WRITE_SIZE must stay ~256 KB (balloon = scratch spill of pins).
//   Structure unchanged: 512 thr, readlane y-broadcast, 8-way fp32 partial
//   combine, Ralston RK2, 3 phases/step (accuracy ladder closed at v15-v17).

#define T_STEPS 64
#define HD 256
#define DD 512
#define NBLK 256

// byte offsets into d_ws
#define WT_B    0u        // 128 KB f16 W~  thread-sliced [j(16)][tid(512)] uint4
#define WR_B    131072u   // 128 KB f16 Whh gate r
#define WZ_B    262144u   // 128 KB f16 Whh gate z
#define WN_B    393216u   // 128 KB f16 Whh gate n
#define BTL_B   524288u   // 256 fp32: b~ = W2@b1 + b2

typedef _Float16 h2 __attribute__((ext_vector_type(2)));
struct H8 { h2 x, y, z, w; };
union PKU { unsigned int u; _Float16 h[2]; };

__device__ __forceinline__ H8 toH8(uint4 u) { return __builtin_bit_cast(H8, u); }

__device__ __forceinline__ float bf2f(unsigned short h) {
  return __uint_as_float(((unsigned int)h) << 16);
}
__device__ __forceinline__ float ldin(const void* p, int i, bool bf) {
  return bf ? bf2f(((const unsigned short*)p)[i]) : ((const float*)p)[i];
}
__device__ __forceinline__ float fast_tanh(float x) {
  float e = __expf(2.f * x);
  return 1.f - __fdividef(2.f, e + 1.f);
}
__device__ __forceinline__ float fast_sigm(float x) {
  return __fdividef(1.f, 1.f + __expf(-x));
}
__device__ __forceinline__ unsigned short f16b(float x) {
  return __builtin_bit_cast(unsigned short, (_Float16)x);
}

#if __has_builtin(__builtin_amdgcn_fdot2)
__device__ __forceinline__ float fdot2(h2 a, h2 b, float c) {
  return __builtin_amdgcn_fdot2(a, b, c, false);
}
#else
__device__ __forceinline__ float fdot2(h2 a, h2 b, float c) {
  return (float)a.x * (float)b.x + ((float)a.y * (float)b.y + c);
}
#endif

// wave-uniform lane broadcast of a 32-bit value -> h2 (result lives in SGPR)
__device__ __forceinline__ h2 RLH2(unsigned int v, int lane) {
  return __builtin_bit_cast(h2, __builtin_amdgcn_readlane((int)v, lane));
}

// semantic register pin: value becomes opaque -> cannot be rematerialized from
// its defining load; allocator must keep it resident (or scratch-spill: canary).
#define PIN4(v) asm volatile("" : "+v"((v).x), "+v"((v).y), "+v"((v).z), "+v"((v).w))

// inline dtype detection: times[t]=batch[2t] monotone with deltas in [0.05,0.15]
// under exactly one of {fp32, bf16} interpretation.
__device__ bool detect_bf(const void* batchv) {
  const float* f = (const float*)batchv;
  const unsigned short* u = (const unsigned short*)batchv;
  bool ok32 = true, okbf = true;
  float p32 = 0.f, pbf = 0.f;
#pragma unroll
  for (int t = 0; t < 8; ++t) {
    float v32 = f[2 * t], d32 = v32 - p32;
    if (!(d32 > 0.03f && d32 < 0.17f)) ok32 = false;
    p32 = v32;
    float vbf = bf2f(u[2 * t]), dbf = vbf - pbf;
    if (!(dbf > 0.03f && dbf < 0.17f)) okbf = false;
    pbf = vbf;
  }
  return okbf && !ok32;
}

// pack 8 fp32 -> uint4 of f16
__device__ __forceinline__ uint4 pack8(const float* s) {
  uint4 pk; PKU a, b;
  a.h[0] = (_Float16)s[0]; a.h[1] = (_Float16)s[1]; pk.x = a.u;
  b.h[0] = (_Float16)s[2]; b.h[1] = (_Float16)s[3]; pk.y = b.u;
  a.h[0] = (_Float16)s[4]; a.h[1] = (_Float16)s[5]; pk.z = a.u;
  b.h[0] = (_Float16)s[6]; b.h[1] = (_Float16)s[7]; pk.w = b.u;
  return pk;
}

// ---------- single fused prep: 256 blocks x 512 threads (v21 layout, unchanged) ----------
// Main thread tid = (w<<6)+l owns outputs 4l+i (i=0..3), k in [32w, 32w+32).
// Fragment j = 4i+q covers k = 32w+8q..+8 (q=0..3).
// For matrix element (rrow, m) (m-th uint4 of row rrow, k=8m..8m+8):
//   slot = (4*(rrow&3)+(m&3))*512 + (m>>2)*64 + (rrow>>2)
__global__ void prep_all(const void* __restrict__ batchv,
                         const void* __restrict__ w1v, const void* __restrict__ w2v,
                         const void* __restrict__ b1v, const void* __restrict__ b2v,
                         const void* __restrict__ whhv, float* __restrict__ wsf) {
  __shared__ float w2row[DD];
  __shared__ float2 pacc[4][128];
  __shared__ float wrow[HD];
  __shared__ float bred[8];
  const bool bf = detect_bf(batchv);
  const int o = blockIdx.x;      // 0..255: W~ output row (also pack-share index)
  const int t = threadIdx.x;     // 0..511

  // --- Part B: this block's 96-item share of the Whh pack (issued first) ---
  if (t < 96) {
    const int g = o * 96 + t;                     // 0..24575
    const int mat = g >> 13;                      // 0=r,1=z,2=n
    const int idx = g & 8191;
    const int rrow = idx >> 5;                    // output row 0..255
    const int m   = idx & 31;                     // m-th uint4 of row, k=8m..8m+8
    const int kb  = m * 8;
    const int srow = mat * 256 + rrow;
    float e[8];
    if (bf) {
      uint4 v = ((const uint4*)whhv)[(srow * HD + kb) >> 3];
      e[0] = bf2f((unsigned short)(v.x & 0xffff)); e[1] = bf2f((unsigned short)(v.x >> 16));
      e[2] = bf2f((unsigned short)(v.y & 0xffff)); e[3] = bf2f((unsigned short)(v.y >> 16));
      e[4] = bf2f((unsigned short)(v.z & 0xffff)); e[5] = bf2f((unsigned short)(v.z >> 16));
      e[6] = bf2f((unsigned short)(v.w & 0xffff)); e[7] = bf2f((unsigned short)(v.w >> 16));
    } else {
      float4 v0 = ((const float4*)whhv)[(srow * HD + kb) >> 2];
      float4 v1 = ((const float4*)whhv)[((srow * HD + kb) >> 2) + 1];
      e[0] = v0.x; e[1] = v0.y; e[2] = v0.z; e[3] = v0.w;
      e[4] = v1.x; e[5] = v1.y; e[6] = v1.z; e[7] = v1.w;
    }
    const unsigned base = (mat == 0) ? WR_B : (mat == 1) ? WZ_B : WN_B;
    const unsigned slot = (unsigned)((4 * (rrow & 3) + (m & 3)) * 512 +
                                     ((m >> 2) << 6) + (rrow >> 2));
    ((uint4*)((char*)wsf + base))[slot] = pack8(e);
  }

  // --- Part A: W~ row o = W2[o,:] @ W1 (4-way m-split, 2 k's per thread) ---
  w2row[t] = ldin(w2v, o * DD + t, bf);
  __syncthreads();
  const int kp = t & 127;        // k-pair index: k = 2*kp, 2*kp+1
  const int h  = t >> 7;         // m-quarter
  float a0 = 0.f, a1 = 0.f;
  if (bf) {
    const unsigned int* w1p = (const unsigned int*)w1v;
#pragma unroll 8
    for (int m0 = 0; m0 < 128; ++m0) {
      const int m = h * 128 + m0;
      unsigned int v = w1p[m * 128 + kp];
      const float w = w2row[m];
      a0 += w * bf2f((unsigned short)(v & 0xffff));
      a1 += w * bf2f((unsigned short)(v >> 16));
    }
  } else {
    const float2* w1p = (const float2*)w1v;
#pragma unroll 8
    for (int m0 = 0; m0 < 128; ++m0) {
      const int m = h * 128 + m0;
      float2 v = w1p[m * 128 + kp];
      const float w = w2row[m];
      a0 += w * v.x; a1 += w * v.y;
    }
  }
  pacc[h][kp] = make_float2(a0, a1);
  // btl partial: sum_m w2row[m]*b1[m]
  {
    float p = w2row[t] * ldin(b1v, t, bf);
    p += __shfl_xor(p, 32); p += __shfl_xor(p, 16); p += __shfl_xor(p, 8);
    p += __shfl_xor(p, 4);  p += __shfl_xor(p, 2);  p += __shfl_xor(p, 1);
    if ((t & 63) == 0) bred[t >> 6] = p;
  }
  __syncthreads();
  if (t < 128) {
    float2 s0 = pacc[0][t], s1 = pacc[1][t], s2 = pacc[2][t], s3 = pacc[3][t];
    wrow[2 * t]     = (s0.x + s1.x) + (s2.x + s3.x);
    wrow[2 * t + 1] = (s0.y + s1.y) + (s2.y + s3.y);
  }
  if (t == 0)
    ((float*)((char*)wsf + BTL_B))[o] =
        (bred[0] + bred[1]) + (bred[2] + bred[3]) + (bred[4] + bred[5]) +
        (bred[6] + bred[7]) + ldin(b2v, o, bf);
  __syncthreads();
  if (t < 32) {
    // t-th uint4 of row o covers k = 8t..8t+8
    const unsigned slot = (unsigned)((4 * (o & 3) + (t & 3)) * 512 +
                                     ((t >> 2) << 6) + (o >> 2));
    ((uint4*)((char*)wsf + WT_B))[slot] = pack8(&wrow[t * 8]);
  }
}

// ---------- main scan kernel (v23) ----------
// Per q (k sub-block of 8): 4 readlanes (SGPR) shared by all 4 outputs.
#define STAGE_Q(Q, W0, W1, W2, W3) { \
  const int lq = lnb + 2 * (Q); \
  const h2 y0 = RLH2(vy.x, lq), y1 = RLH2(vy.y, lq); \
  const h2 y2 = RLH2(vy.x, lq + 1), y3 = RLH2(vy.y, lq + 1); \
  { H8 wv = toH8(W0); a0 = fdot2(wv.x, y0, a0); a0 = fdot2(wv.y, y1, a0); \
                      a0 = fdot2(wv.z, y2, a0); a0 = fdot2(wv.w, y3, a0); } \
  { H8 wv = toH8(W1); a1 = fdot2(wv.x, y0, a1); a1 = fdot2(wv.y, y1, a1); \
                      a1 = fdot2(wv.z, y2, a1); a1 = fdot2(wv.w, y3, a1); } \
  { H8 wv = toH8(W2); a2 = fdot2(wv.x, y0, a2); a2 = fdot2(wv.y, y1, a2); \
                      a2 = fdot2(wv.z, y2, a2); a2 = fdot2(wv.w, y3, a2); } \
  { H8 wv = toH8(W3); a3 = fdot2(wv.x, y0, a3); a3 = fdot2(wv.y, y1, a3); \
                      a3 = fdot2(wv.z, y2, a3); a3 = fdot2(wv.w, y3, a3); } }

#define GRU_Q(Q, Z0, Z1, Z2, Z3, R0, R1, R2, R3) { \
  const int lq = lnb + 2 * (Q); \
  const h2 y0 = RLH2(vy.x, lq), y1 = RLH2(vy.y, lq); \
  const h2 y2 = RLH2(vy.x, lq + 1), y3 = RLH2(vy.y, lq + 1); \
  uint4 n0 = nlds[((Q) + 0) * 512 + tid],  n1 = nlds[((Q) + 4) * 512 + tid]; \
  uint4 n2 = nlds[((Q) + 8) * 512 + tid],  n3 = nlds[((Q) + 12) * 512 + tid]; \
  { H8 v_ = toH8(Z0); gz0 = fdot2(v_.x, y0, gz0); gz0 = fdot2(v_.y, y1, gz0); \
                      gz0 = fdot2(v_.z, y2, gz0); gz0 = fdot2(v_.w, y3, gz0); } \
  { H8 v_ = toH8(R0); gr0 = fdot2(v_.x, y0, gr0); gr0 = fdot2(v_.y, y1, gr0); \
                      gr0 = fdot2(v_.z, y2, gr0); gr0 = fdot2(v_.w, y3, gr0); } \
  { H8 v_ = toH8(n0); gn0 = fdot2(v_.x, y0, gn0); gn0 = fdot2(v_.y, y1, gn0); \
                      gn0 = fdot2(v_.z, y2, gn0); gn0 = fdot2(v_.w, y3, gn0); } \
  { H8 v_ = toH8(Z1); gz1 = fdot2(v_.x, y0, gz1); gz1 = fdot2(v_.y, y1, gz1); \
                      gz1 = fdot2(v_.z, y2, gz1); gz1 = fdot2(v_.w, y3, gz1); } \
  { H8 v_ = toH8(R1); gr1 = fdot2(v_.x, y0, gr1); gr1 = fdot2(v_.y, y1, gr1); \
                      gr1 = fdot2(v_.z, y2, gr1); gr1 = fdot2(v_.w, y3, gr1); } \
  { H8 v_ = toH8(n1); gn1 = fdot2(v_.x, y0, gn1); gn1 = fdot2(v_.y, y1, gn1); \
                      gn1 = fdot2(v_.z, y2, gn1); gn1 = fdot2(v_.w, y3, gn1); } \
  { H8 v_ = toH8(Z2); gz2 = fdot2(v_.x, y0, gz2); gz2 = fdot2(v_.y, y1, gz2); \
                      gz2 = fdot2(v_.z, y2, gz2); gz2 = fdot2(v_.w, y3, gz2); } \
  { H8 v_ = toH8(R2); gr2 = fdot2(v_.x, y0, gr2); gr2 = fdot2(v_.y, y1, gr2); \
                      gr2 = fdot2(v_.z, y2, gr2); gr2 = fdot2(v_.w, y3, gr2); } \
  { H8 v_ = toH8(n2); gn2 = fdot2(v_.x, y0, gn2); gn2 = fdot2(v_.y, y1, gn2); \
                      gn2 = fdot2(v_.z, y2, gn2); gn2 = fdot2(v_.w, y3, gn2); } \
  { H8 v_ = toH8(Z3); gz3 = fdot2(v_.x, y0, gz3); gz3 = fdot2(v_.y, y1, gz3); \
                      gz3 = fdot2(v_.z, y2, gz3); gz3 = fdot2(v_.w, y3, gz3); } \
  { H8 v_ = toH8(R3); gr3 = fdot2(v_.x, y0, gr3); gr3 = fdot2(v_.y, y1, gr3); \
                      gr3 = fdot2(v_.z, y2, gr3); gr3 = fdot2(v_.w, y3, gr3); } \
  { H8 v_ = toH8(n3); gn3 = fdot2(v_.x, y0, gn3); gn3 = fdot2(v_.y, y1, gn3); \
                      gn3 = fdot2(v_.z, y2, gn3); gn3 = fdot2(v_.w, y3, gn3); } }

extern "C" __global__ __launch_bounds__(512)
__attribute__((amdgpu_waves_per_eu(2, 2)))
void ode_rnn_main(const void* __restrict__ batchv, const void* __restrict__ maskv,
                  const void* __restrict__ wihv, const void* __restrict__ bihv,
                  const void* __restrict__ bhhv, const float* __restrict__ wsf,
                  void* __restrict__ outv) {
  extern __shared__ uint4 nlds[];                 // 8192 uint4 = 128 KB: gate-n
  __shared__ float psA[2048], psB[2048], psC[2048];   // fp32 partials [w*256+o]
  __shared__ __align__(8) unsigned short ybuf[HD];    // y state (f16)
  __shared__ float times_s[T_STEPS], xsrow[T_STEPS], msrow[T_STEPS];

  const int tid = threadIdx.x;          // 0..511
  const int l   = tid & 63;
  const int w   = tid >> 6;             // wave 0..7 = k-segment [32w, 32w+32)
  const int lnb = __builtin_amdgcn_readfirstlane(w << 3);  // readlane base: 8w
  const int row = blockIdx.x;
  const bool bf = detect_bf(batchv);

  // gate n -> LDS FIRST (keeps staging's transient regs off the pin peak)
  {
    const uint4* src = (const uint4*)((const char*)wsf + WN_B);
#pragma unroll
    for (int i = 0; i < 16; ++i) nlds[i * 512 + tid] = src[i * 512 + tid];
  }

  // pinned weights: W~ + gate z + gate r = 48 uint4 = 192 VGPR, asm-pinned so
  // the allocator CANNOT rematerialize them as per-step L2 streams.
  const uint4* pwt = (const uint4*)((const char*)wsf + WT_B) + tid;
  const uint4* pwz = (const uint4*)((const char*)wsf + WZ_B) + tid;
  const uint4* pwr = (const uint4*)((const char*)wsf + WR_B) + tid;
  uint4 wt0 = pwt[0 * 512], wt1 = pwt[1 * 512], wt2 = pwt[2 * 512], wt3 = pwt[3 * 512];
  uint4 wt4 = pwt[4 * 512], wt5 = pwt[5 * 512], wt6 = pwt[6 * 512], wt7 = pwt[7 * 512];
  uint4 wt8 = pwt[8 * 512], wt9 = pwt[9 * 512], wt10 = pwt[10 * 512], wt11 = pwt[11 * 512];
  uint4 wt12 = pwt[12 * 512], wt13 = pwt[13 * 512], wt14 = pwt[14 * 512], wt15 = pwt[15 * 512];
  PIN4(wt0); PIN4(wt1); PIN4(wt2); PIN4(wt3); PIN4(wt4); PIN4(wt5); PIN4(wt6); PIN4(wt7);
  PIN4(wt8); PIN4(wt9); PIN4(wt10); PIN4(wt11); PIN4(wt12); PIN4(wt13); PIN4(wt14); PIN4(wt15);
  uint4 zt0 = pwz[0 * 512], zt1 = pwz[1 * 512], zt2 = pwz[2 * 512], zt3 = pwz[3 * 512];
  uint4 zt4 = pwz[4 * 512], zt5 = pwz[5 * 512], zt6 = pwz[6 * 512], zt7 = pwz[7 * 512];
  uint4 zt8 = pwz[8 * 512], zt9 = pwz[9 * 512], zt10 = pwz[10 * 512], zt11 = pwz[11 * 512];
  uint4 zt12 = pwz[12 * 512], zt13 = pwz[13 * 512], zt14 = pwz[14 * 512], zt15 = pwz[15 * 512];
  PIN4(zt0); PIN4(zt1); PIN4(zt2); PIN4(zt3); PIN4(zt4); PIN4(zt5); PIN4(zt6); PIN4(zt7);
  PIN4(zt8); PIN4(zt9); PIN4(zt10); PIN4(zt11); PIN4(zt12); PIN4(zt13); PIN4(zt14); PIN4(zt15);
  uint4 rt0 = pwr[0 * 512], rt1 = pwr[1 * 512], rt2 = pwr[2 * 512], rt3 = pwr[3 * 512];
  uint4 rt4 = pwr[4 * 512], rt5 = pwr[5 * 512], rt6 = pwr[6 * 512], rt7 = pwr[7 * 512];
  uint4 rt8 = pwr[8 * 512], rt9 = pwr[9 * 512], rt10 = pwr[10 * 512], rt11 = pwr[11 * 512];
  uint4 rt12 = pwr[12 * 512], rt13 = pwr[13 * 512], rt14 = pwr[14 * 512], rt15 = pwr[15 * 512];
  PIN4(rt0); PIN4(rt1); PIN4(rt2); PIN4(rt3); PIN4(rt4); PIN4(rt5); PIN4(rt6); PIN4(rt7);
  PIN4(rt8); PIN4(rt9); PIN4(rt10); PIN4(rt11); PIN4(rt12); PIN4(rt13); PIN4(rt14); PIN4(rt15);

  // epilogue constants: only the per-output combine thread (o = tid < 256)
  float btl_r = 0.f, wir = 0.f, wiz = 0.f, win = 0.f;
  float br2 = 0.f, bz2 = 0.f, bin_ = 0.f, bhn = 0.f;
  if (tid < HD) {
    btl_r = ((const float*)((const char*)wsf + BTL_B))[tid];
    wir = ldin(wihv, tid, bf); wiz = ldin(wihv, 256 + tid, bf); win = ldin(wihv, 512 + tid, bf);
    br2 = ldin(bihv, tid, bf) + ldin(bhhv, tid, bf);
    bz2 = ldin(bihv, 256 + tid, bf) + ldin(bhhv, 256 + tid, bf);
    bin_ = ldin(bihv, 512 + tid, bf);
    bhn  = ldin(bhhv, 512 + tid, bf);
  }

  if (tid < T_STEPS) {
    times_s[tid] = ldin(batchv, tid * 2, bf);
    xsrow[tid]   = ldin(batchv, row * (T_STEPS * 2) + tid * 2 + 1, bf);
    msrow[tid]   = ldin(maskv, row * T_STEPS + tid, bf);
  }
  if (tid < HD) ybuf[tid] = 0;
  __syncthreads();

  float yreg = 0.f, kac = 0.f;          // live on combine threads (tid<256)

  float tprev = 0.f;
#pragma unroll 1
  for (int step = 0; step < T_STEPS; ++step) {
    const float tcur = times_s[step];
    const float hdt = tcur - tprev;
    tprev = tcur;

    // ---- Ralston RK2 stage 1: k1; arg2 = y + (2h/3) k1 ----
    {
      const uint2 vy = *(const uint2*)&ybuf[4 * l];   // lane l: y f16[4l..4l+4)
      float a0 = 0.f, a1 = 0.f, a2 = 0.f, a3 = 0.f;
      STAGE_Q(0, wt0, wt4, wt8, wt12)
      STAGE_Q(1, wt1, wt5, wt9, wt13)
      STAGE_Q(2, wt2, wt6, wt10, wt14)
      STAGE_Q(3, wt3, wt7, wt11, wt15)
      *(float4*)&psA[(w << 8) + 4 * l] = make_float4(a0, a1, a2, a3);
      __syncthreads();
      if (tid < HD) {
        float s = ((psA[tid] + psA[256 + tid]) + (psA[512 + tid] + psA[768 + tid])) +
                  ((psA[1024 + tid] + psA[1280 + tid]) + (psA[1536 + tid] + psA[1792 + tid]));
        float vv = fast_tanh(s + btl_r);
        kac = vv;
        ybuf[tid] = f16b(yreg + (2.f / 3.f) * hdt * vv);
      }
      __syncthreads();
    }

    // ---- Ralston RK2 stage 2: k2; y+ = y + h (k1/4 + 3 k2/4) ----
    {
      const uint2 vy = *(const uint2*)&ybuf[4 * l];
      float a0 = 0.f, a1 = 0.f, a2 = 0.f, a3 = 0.f;
      STAGE_Q(0, wt0, wt4, wt8, wt12)
      STAGE_Q(1, wt1, wt5, wt9, wt13)
      STAGE_Q(2, wt2, wt6, wt10, wt14)
      STAGE_Q(3, wt3, wt7, wt11, wt15)
      *(float4*)&psA[(w << 8) + 4 * l] = make_float4(a0, a1, a2, a3);
      __syncthreads();
      if (tid < HD) {
        float s = ((psA[tid] + psA[256 + tid]) + (psA[512 + tid] + psA[768 + tid])) +
                  ((psA[1024 + tid] + psA[1280 + tid]) + (psA[1536 + tid] + psA[1792 + tid]));
        float vv = fast_tanh(s + btl_r);
        yreg = yreg + hdt * (0.25f * kac + 0.75f * vv);
        ybuf[tid] = f16b(yreg);
      }
      __syncthreads();
    }

    // ---- GRU ----
    {
      const uint2 vy = *(const uint2*)&ybuf[4 * l];
      float gz0 = 0.f, gz1 = 0.f, gz2 = 0.f, gz3 = 0.f;
      float gr0 = 0.f, gr1 = 0.f, gr2 = 0.f, gr3 = 0.f;
      float gn0 = 0.f, gn1 = 0.f, gn2 = 0.f, gn3 = 0.f;
      GRU_Q(0, zt0, zt4, zt8, zt12, rt0, rt4, rt8, rt12)
      GRU_Q(1, zt1, zt5, zt9, zt13, rt1, rt5, rt9, rt13)
      GRU_Q(2, zt2, zt6, zt10, zt14, rt2, rt6, rt10, rt14)
      GRU_Q(3, zt3, zt7, zt11, zt15, rt3, rt7, rt11, rt15)
      *(float4*)&psA[(w << 8) + 4 * l] = make_float4(gz0, gz1, gz2, gz3);
      *(float4*)&psB[(w << 8) + 4 * l] = make_float4(gr0, gr1, gr2, gr3);
      *(float4*)&psC[(w << 8) + 4 * l] = make_float4(gn0, gn1, gn2, gn3);
      __syncthreads();
      if (tid < HD) {
        float Za = ((psA[tid] + psA[256 + tid]) + (psA[512 + tid] + psA[768 + tid])) +
                   ((psA[1024 + tid] + psA[1280 + tid]) + (psA[1536 + tid] + psA[1792 + tid]));
        float Ra = ((psB[tid] + psB[256 + tid]) + (psB[512 + tid] + psB[768 + tid])) +
                   ((psB[1024 + tid] + psB[1280 + tid]) + (psB[1536 + tid] + psB[1792 + tid]));
        float Na = ((psC[tid] + psC[256 + tid]) + (psC[512 + tid] + psC[768 + tid])) +
                   ((psC[1024 + tid] + psC[1280 + tid]) + (psC[1536 + tid] + psC[1792 + tid]));
        const float xv = xsrow[step], mm = msrow[step];
        const float hp = yreg;
        float rr = fast_sigm(xv * wir + br2 + Ra);
        float zz = fast_sigm(xv * wiz + bz2 + Za);
        float nn = fast_tanh(xv * win + bin_ + rr * (Na + bhn));
        float ht = (1.f - zz) * nn + zz * hp;
        yreg = mm * ht + (1.f - mm) * hp;
        ybuf[tid] = f16b(yreg);
      }
      __syncthreads();
    }
  }

  if (tid < HD) {
    int idx = row * HD + tid;
    if (bf) ((__hip_bfloat16*)outv)[idx] = __float2bfloat16(yreg);
    else    ((float*)outv)[idx] = yreg;
  }
}

extern "C" void kernel_launch(void* const* d_in, const int* in_sizes, int n_in,
                              void* d_out, int out_size, void* d_ws, size_t ws_size,
                              hipStream_t stream) {
  // d_in order: 0 batch, 1 mask, 2 W1, 3 b1, 4 W2, 5 b2, 6 W_ih, 7 b_ih, 8 W_hh, 9 b_hh
  float* ws = (float*)d_ws;
  prep_all<<<256, 512, 0, stream>>>(d_in[0], d_in[2], d_in[4], d_in[3], d_in[5],
                                    d_in[8], ws);
  (void)hipFuncSetAttribute((const void*)ode_rnn_main,
                            hipFuncAttributeMaxDynamicSharedMemorySize, 131072);
  ode_rnn_main<<<NBLK, 512, 131072, stream>>>(d_in[0], d_in[1], d_in[6], d_in[7], d_in[9],
                                              ws, d_out);
}